// Round 7
// baseline (320.571 us; speedup 1.0000x reference)
//
#include <hip/hip_runtime.h>
#include <hip/hip_bf16.h>
#include <hip/hip_cooperative_groups.h>

namespace cg = cooperative_groups;

// SelfAttention: B=2, S=2048, H=16, D=64, E=1024
// ONE cooperative kernel, 512 blocks x 512 threads, 3 phases + 2 grid.sync():
//   phase 1 proj   (job = (n,h,s-tile/128)): QKV linears; Q pre-scaled 1/32;
//                  Q/K d-channels sigma-permuted (QK^T invariant) -> 16B stores;
//                  V stored key-permuted (kappa).
//   phase 2 attn   (job = (n,h,q-tile/128)): S^T-form flash attn, K=32 PV via
//                  kappa, no-max softmax, mask = additive bias in S-acc init,
//                  lsum via ones-MFMA, waves 0-3/4-7 split the key halves,
//                  LDS combine at end.
//   phase 3 outproj(job = (row-tile/128, col-tile/64)): 128x64 double-buffered
//                  GEMM + bias, Wout fp32->bf16 inline.
// Fallback: if cooperative launch fails, the same bodies run as 3 kernels.
// ws: Qb[0,8M) Kb[8M,16M) Vt[16M,24M) Og[24M,32M).

#define NHB 16
#define HS  64
#define EMB 1024
#define BB  2
#define SS  2048
#define NT  (SS / 64)

typedef __bf16 bf16_t;
typedef bf16_t bf16x8 __attribute__((ext_vector_type(8)));
typedef bf16_t bf16x4 __attribute__((ext_vector_type(4)));
typedef float  f32x4  __attribute__((ext_vector_type(4)));

__device__ __forceinline__ f32x4 mfma16(bf16x8 a, bf16x8 b, f32x4 c) {
    return __builtin_amdgcn_mfma_f32_16x16x32_bf16(a, b, c, 0, 0, 0);
}

// ---------------------------------------------------------------------------
// Phase 1: proj. bid -> (s-tile, h, n); 128 s-rows/block. LDS: 46080 B.
// ---------------------------------------------------------------------------
__device__ __forceinline__ void proj_body(
    unsigned char* smem_raw, int bid,
    const float* __restrict__ queries, const float* __restrict__ keys,
    const float* __restrict__ values,
    const float* __restrict__ Wq, const float* __restrict__ Wk,
    const float* __restrict__ Wv,
    bf16_t* __restrict__ Qb, bf16_t* __restrict__ Kb, bf16_t* __restrict__ Vt)
{
    auto Ws = (bf16_t(*)[64][72])(smem_raw);          // [3][64][72] = 27648 B
    auto Xs = (bf16_t(*)[72])(smem_raw + 27648);      // [128][72]  = 18432 B

    const int tid  = threadIdx.x;
    const int wave = tid >> 6, lane = tid & 63;
    const int q4 = lane >> 4, l16 = lane & 15;
    const int s0 = (bid & 15) * 128;
    const int h  = (bid >> 4) & 15, n = bid >> 8;

    // stage the three 64x64 weight matrices (3072 float4 chunks / 512 thr)
    #pragma unroll
    for (int i = 0; i < 6; ++i) {
        int g = i * 512 + tid;
        int mW = g >> 10;                 // uniform per i
        int idx4 = g & 1023;
        const float* wp = (mW == 0) ? Wq : (mW == 1) ? Wk : Wv;
        float4 v = ((const float4*)wp)[idx4];
        int r = idx4 >> 4, c = (idx4 & 15) * 4;
        Ws[mW][r][c+0] = (bf16_t)v.x; Ws[mW][r][c+1] = (bf16_t)v.y;
        Ws[mW][r][c+2] = (bf16_t)v.z; Ws[mW][r][c+3] = (bf16_t)v.w;
    }

    const size_t headBase = (size_t)(n * NHB + h) * SS * HS;

    float4 gx[4];
    auto loadX = [&](const float* xp) {
        #pragma unroll
        for (int i = 0; i < 4; ++i) {
            int idx4 = i * 512 + tid;                 // 2048 chunks: 128 x 16
            int r = idx4 >> 4, c = (idx4 & 15) * 4;
            gx[i] = *(const float4*)&xp[((size_t)(n * SS + s0 + r)) * EMB + h * HS + c];
        }
    };
    loadX(queries);

    for (int p = 0; p < 3; ++p) {
        __syncthreads();                 // Xs free (and Ws ready when p==0)
        #pragma unroll
        for (int i = 0; i < 4; ++i) {
            int idx4 = i * 512 + tid;
            int r = idx4 >> 4, c = (idx4 & 15) * 4;
            Xs[r][c+0] = (bf16_t)gx[i].x; Xs[r][c+1] = (bf16_t)gx[i].y;
            Xs[r][c+2] = (bf16_t)gx[i].z; Xs[r][c+3] = (bf16_t)gx[i].w;
        }
        if (p == 0) loadX(keys);
        else if (p == 1) loadX(values);  // in flight across barrier + compute
        __syncthreads();

        bf16x8 xf[2], wf[4][2];
        #pragma unroll
        for (int kk = 0; kk < 2; ++kk)
            xf[kk] = *(const bf16x8*)&Xs[wave * 16 + l16][kk * 32 + q4 * 8];
        #pragma unroll
        for (int ct = 0; ct < 4; ++ct)
            #pragma unroll
            for (int kk = 0; kk < 2; ++kk)
                wf[ct][kk] = *(const bf16x8*)&Ws[p][ct * 16 + l16][kk * 32 + q4 * 8];

        if (p < 2) {
            // A=W (m=channel), B=X^T (n=s): C col = s(l16), regs = channel.
            // sigma gather: phys channel = q4*16 + ct*4 + i -> two 16B stores.
            bf16_t* dst = (p == 0) ? Qb : Kb;
            const float sc = (p == 0) ? 0.03125f : 1.0f;   // 1/sqrt(EMB) into Q
            bf16x8 lo, hi;
            #pragma unroll
            for (int ct = 0; ct < 4; ++ct) {
                f32x4 acc = {};
                acc = mfma16(wf[ct][0], xf[0], acc);
                acc = mfma16(wf[ct][1], xf[1], acc);
                #pragma unroll
                for (int i = 0; i < 4; ++i) {
                    bf16_t v = (bf16_t)(acc[i] * sc);
                    if (ct < 2) lo[ct * 4 + i] = v;
                    else        hi[(ct - 2) * 4 + i] = v;
                }
            }
            bf16_t* rp = dst + headBase
                + (size_t)(s0 + wave * 16 + l16) * HS + q4 * 16;
            *(bf16x8*)rp = lo;
            *(bf16x8*)(rp + 8) = hi;
        } else {
            // A=X (m=s), B=W^T (n=channel): C col = channel, regs = s.
            #pragma unroll
            for (int ct = 0; ct < 4; ++ct) {
                f32x4 acc = {};
                acc = mfma16(xf[0], wf[ct][0], acc);
                acc = mfma16(xf[1], wf[ct][1], acc);
                bf16x4 pk;
                #pragma unroll
                for (int i = 0; i < 4; ++i) pk[i] = (bf16_t)acc[i];
                *(bf16x4*)&Vt[headBase + (size_t)(ct * 16 + l16) * SS
                              + s0 + (wave >> 1) * 32 + q4 * 8 + (wave & 1) * 4] = pk;
            }
        }
    }
}

// ---------------------------------------------------------------------------
// Phase 2: attn. bid -> (q-tile, h, n). LDS: 37376 B.
// ---------------------------------------------------------------------------
__device__ __forceinline__ void attn_body(
    unsigned char* smem_raw, int bid,
    const bf16_t* __restrict__ Qb, const bf16_t* __restrict__ Kb,
    const bf16_t* __restrict__ Vt, const int* __restrict__ mask,
    bf16_t* __restrict__ Og)
{
    auto Ks = (bf16_t(*)[64][72])(smem_raw);            // [2][key][d]
    auto Vs = (bf16_t(*)[64][72])(smem_raw + 18432);    // [2][d][kappa-key]
    auto Ms = (float(*)[64])(smem_raw + 36864);         // [2][64] additive bias
    float* fbuf = (float*)smem_raw;                      // combine: 32 KB
    float* lbuf = (float*)(smem_raw + 32768);            // combine: 2 KB

    const int tid = threadIdx.x;
    const int w = tid >> 6, lane = tid & 63;
    const int q4 = lane >> 4, l16 = lane & 15;
    const int wq = w & 3, wk = w >> 2;
    const int qt = bid & 15, h = (bid >> 4) & 15, n = bid >> 8;
    const size_t headBase = (size_t)(n * NHB + h) * SS * HS;
    const int* mrow = mask + n * SS;

    const int sr = tid >> 3, sc = (tid & 7) * 8;
    const bf16_t* kb_src = Kb + headBase + (size_t)sr * HS + sc;
    const bf16_t* vt_src = Vt + headBase + (size_t)sr * SS + sc;

    bf16x8 bq[2][2];
    #pragma unroll
    for (int st = 0; st < 2; ++st) {
        const bf16_t* qptr = Qb + headBase
            + (size_t)(qt * 128 + wq * 32 + st * 16 + l16) * HS;
        bq[st][0] = *(const bf16x8*)&qptr[q4 * 8];
        bq[st][1] = *(const bf16x8*)&qptr[32 + q4 * 8];
    }

    bf16x8 ones;
    #pragma unroll
    for (int i = 0; i < 8; ++i) ones[i] = (bf16_t)1.0f;

    f32x4 oaccT[2][4] = {};
    f32x4 lacc[2] = {};

    *(bf16x8*)&Ks[0][sr][sc] = *(const bf16x8*)kb_src;
    *(bf16x8*)&Vs[0][sr][sc] = *(const bf16x8*)vt_src;
    if (tid < 64) Ms[0][tid] = mrow[tid] ? 0.0f : -3e38f;
    __syncthreads();

    for (int kt = 0; kt < NT; ++kt) {
        const int cur = kt & 1;
        const bool has_next = (kt + 1) < NT;
        bf16x8 gk, gv; float gm = 0.f;
        if (has_next) {
            const int k0n = (kt + 1) * 64;
            gk = *(const bf16x8*)(kb_src + (size_t)k0n * HS);
            gv = *(const bf16x8*)(vt_src + k0n);
            if (tid < 64) gm = mrow[k0n + tid] ? 0.0f : -3e38f;
        }

        // S^T = bias + K.Q^T over this wave's 32-key half
        f32x4 sacc[2][2];
        #pragma unroll
        for (int c2 = 0; c2 < 2; ++c2) {
            const int ct = wk * 2 + c2;
            float4 bias = *(const float4*)&Ms[cur][ct * 16 + q4 * 4];
            f32x4 b4 = {bias.x, bias.y, bias.z, bias.w};
            sacc[0][c2] = b4; sacc[1][c2] = b4;
            bf16x8 ak0 = *(const bf16x8*)&Ks[cur][ct * 16 + l16][q4 * 8];
            bf16x8 ak1 = *(const bf16x8*)&Ks[cur][ct * 16 + l16][32 + q4 * 8];
            #pragma unroll
            for (int st = 0; st < 2; ++st) {
                sacc[st][c2] = mfma16(ak0, bq[st][0], sacc[st][c2]);
                sacc[st][c2] = mfma16(ak1, bq[st][1], sacc[st][c2]);
            }
        }

        // P = exp(S): single fast-exp, no mask mul, no scalar lsum
        bf16x4 pv[2][2];
        #pragma unroll
        for (int c2 = 0; c2 < 2; ++c2)
            #pragma unroll
            for (int st = 0; st < 2; ++st) {
                bf16x4 pk;
                #pragma unroll
                for (int j = 0; j < 4; ++j)
                    pk[j] = (bf16_t)__expf(sacc[st][c2][j]);
                pv[st][c2] = pk;
            }

        // O^T += V^T.P^T ; lsum += ones.P^T
        bf16x8 pa[2];
        #pragma unroll
        for (int st = 0; st < 2; ++st)
            pa[st] = __builtin_shufflevector(pv[st][0], pv[st][1],
                                             0, 1, 2, 3, 4, 5, 6, 7);
        #pragma unroll
        for (int dt = 0; dt < 4; ++dt) {
            bf16x8 av = *(const bf16x8*)&Vs[cur][dt * 16 + l16][wk * 32 + q4 * 8];
            oaccT[0][dt] = mfma16(av, pa[0], oaccT[0][dt]);
            oaccT[1][dt] = mfma16(av, pa[1], oaccT[1][dt]);
        }
        lacc[0] = mfma16(ones, pa[0], lacc[0]);
        lacc[1] = mfma16(ones, pa[1], lacc[1]);

        if (has_next) {
            const int nxt = 1 - cur;
            *(bf16x8*)&Ks[nxt][sr][sc] = gk;
            *(bf16x8*)&Vs[nxt][sr][sc] = gv;
            if (tid < 64) Ms[nxt][tid] = gm;
        }
        __syncthreads();
    }

    float ls[2] = {lacc[0][0], lacc[1][0]};

    // combine partner halves: waves 4-7 publish, waves 0-3 reduce + store
    if (w >= 4) {
        const int lanecol = wq * 64 + lane;
        #pragma unroll
        for (int st = 0; st < 2; ++st) {
            #pragma unroll
            for (int dt = 0; dt < 4; ++dt)
                #pragma unroll
                for (int j = 0; j < 4; ++j)
                    fbuf[(st * 16 + dt * 4 + j) * 256 + lanecol] = oaccT[st][dt][j];
            lbuf[st * 256 + lanecol] = ls[st];
        }
    }
    __syncthreads();
    if (w < 4) {
        const int lanecol = wq * 64 + lane;
        #pragma unroll
        for (int st = 0; st < 2; ++st) {
            #pragma unroll
            for (int dt = 0; dt < 4; ++dt)
                #pragma unroll
                for (int j = 0; j < 4; ++j)
                    oaccT[st][dt][j] += fbuf[(st * 16 + dt * 4 + j) * 256 + lanecol];
            ls[st] += lbuf[st * 256 + lanecol];
        }
        #pragma unroll
        for (int st = 0; st < 2; ++st) {
            const float inv = 1.f / ls[st];
            const int qrow = qt * 128 + wq * 32 + st * 16 + l16;
            bf16_t* obase = Og + ((size_t)(n * SS + qrow)) * EMB + h * HS;
            #pragma unroll
            for (int dt = 0; dt < 4; ++dt) {
                bf16x4 ov;
                #pragma unroll
                for (int j = 0; j < 4; ++j) ov[j] = (bf16_t)(oaccT[st][dt][j] * inv);
                *(bf16x4*)&obase[dt * 16 + q4 * 4] = ov;
            }
        }
    }
}

// ---------------------------------------------------------------------------
// Phase 3: outproj. bid -> (row-tile 128, col-tile 64). LDS: 55296 B.
// ---------------------------------------------------------------------------
__device__ __forceinline__ void outproj_body(
    unsigned char* smem_raw, int bid,
    const bf16_t* __restrict__ Og, const float* __restrict__ Wout,
    const float* __restrict__ bout, float* __restrict__ out)
{
    auto As = (bf16_t(*)[128][72])(smem_raw);           // [2][128][72] 36864 B
    auto Bs = (bf16_t(*)[64][72])(smem_raw + 36864);    // [2][64][72]  18432 B

    const int tid = threadIdx.x;
    const int w = tid >> 6, lane = tid & 63;
    const int q4 = lane >> 4, l16 = lane & 15;
    const int wr = w >> 1, wc = w & 1;
    const int t0 = (bid & 31) * 128, c0 = (bid >> 5) * 64;

    const int sr0 = tid >> 3, sc0 = (tid & 7) * 8;
    const int sr1 = sr0 + 64;
    const bf16_t* a0 = Og + (size_t)(t0 + sr0) * EMB + sc0;
    const bf16_t* a1 = Og + (size_t)(t0 + sr1) * EMB + sc0;
    const float*  b0 = Wout + (size_t)(c0 + sr0) * EMB + sc0;

    auto cvt8 = [](float4 x, float4 y) {
        bf16x8 r;
        r[0] = (bf16_t)x.x; r[1] = (bf16_t)x.y; r[2] = (bf16_t)x.z; r[3] = (bf16_t)x.w;
        r[4] = (bf16_t)y.x; r[5] = (bf16_t)y.y; r[6] = (bf16_t)y.z; r[7] = (bf16_t)y.w;
        return r;
    };

    f32x4 acc[2][2] = {};

    *(bf16x8*)&As[0][sr0][sc0] = *(const bf16x8*)a0;
    *(bf16x8*)&As[0][sr1][sc0] = *(const bf16x8*)a1;
    *(bf16x8*)&Bs[0][sr0][sc0] = cvt8(*(const float4*)b0, *(const float4*)(b0 + 4));
    __syncthreads();

    const int NE = EMB / 64;
    for (int et = 0; et < NE; ++et) {
        const int cur = et & 1;
        const bool has_next = (et + 1) < NE;
        bf16x8 ga0, ga1; float4 gb0, gb1;
        if (has_next) {
            const int e0 = (et + 1) * 64;
            ga0 = *(const bf16x8*)(a0 + e0); ga1 = *(const bf16x8*)(a1 + e0);
            gb0 = *(const float4*)(b0 + e0); gb1 = *(const float4*)(b0 + e0 + 4);
        }

        bf16x8 af[2][2], bfr[2][2];
        #pragma unroll
        for (int st = 0; st < 2; ++st)
            #pragma unroll
            for (int kk = 0; kk < 2; ++kk)
                af[st][kk] = *(const bf16x8*)&As[cur][wr * 32 + st * 16 + l16][kk * 32 + q4 * 8];
        #pragma unroll
        for (int ct = 0; ct < 2; ++ct)
            #pragma unroll
            for (int kk = 0; kk < 2; ++kk)
                bfr[ct][kk] = *(const bf16x8*)&Bs[cur][wc * 32 + ct * 16 + l16][kk * 32 + q4 * 8];
        #pragma unroll
        for (int st = 0; st < 2; ++st)
            #pragma unroll
            for (int ct = 0; ct < 2; ++ct) {
                acc[st][ct] = mfma16(af[st][0], bfr[ct][0], acc[st][ct]);
                acc[st][ct] = mfma16(af[st][1], bfr[ct][1], acc[st][ct]);
            }

        if (has_next) {
            const int nxt = 1 - cur;
            *(bf16x8*)&As[nxt][sr0][sc0] = ga0;
            *(bf16x8*)&As[nxt][sr1][sc0] = ga1;
            *(bf16x8*)&Bs[nxt][sr0][sc0] = cvt8(gb0, gb1);
        }
        __syncthreads();
    }

    #pragma unroll
    for (int ct = 0; ct < 2; ++ct) {
        const int c = c0 + wc * 32 + ct * 16 + l16;
        const float bias = bout[c];
        #pragma unroll
        for (int st = 0; st < 2; ++st)
            #pragma unroll
            for (int i = 0; i < 4; ++i)
                out[(size_t)(t0 + wr * 32 + st * 16 + q4 * 4 + i) * EMB + c]
                    = acc[st][ct][i] + bias;
    }
}

// ---------------------------------------------------------------------------
// Fused cooperative kernel: 512 blocks x 512 threads, 2 grid syncs.
// ---------------------------------------------------------------------------
__global__ __launch_bounds__(512) void fused_kernel(
    const float* values, const float* keys, const float* queries,
    const int* mask, const float* Wq, const float* Wk, const float* Wv,
    const float* Wout, const float* bout, float* out,
    bf16_t* Qb, bf16_t* Kb, bf16_t* Vt, bf16_t* Og)
{
    __shared__ __align__(16) unsigned char smem[55296];
    cg::grid_group grid = cg::this_grid();
    const int bid = blockIdx.x;

    proj_body(smem, bid, queries, keys, values, Wq, Wk, Wv, Qb, Kb, Vt);
    grid.sync();
    attn_body(smem, bid, Qb, Kb, Vt, mask, Og);
    grid.sync();
    outproj_body(smem, bid, Og, Wout, bout, out);
}

// ---------------------------------------------------------------------------
// Fallback kernels (same bodies, 3 separate launches).
// ---------------------------------------------------------------------------
__global__ __launch_bounds__(512) void proj_k(
    const float* queries, const float* keys, const float* values,
    const float* Wq, const float* Wk, const float* Wv,
    bf16_t* Qb, bf16_t* Kb, bf16_t* Vt)
{
    __shared__ __align__(16) unsigned char smem[46080];
    proj_body(smem, blockIdx.x, queries, keys, values, Wq, Wk, Wv, Qb, Kb, Vt);
}

__global__ __launch_bounds__(512) void attn_k(
    const bf16_t* Qb, const bf16_t* Kb, const bf16_t* Vt,
    const int* mask, bf16_t* Og)
{
    __shared__ __align__(16) unsigned char smem[37376];
    attn_body(smem, blockIdx.x, Qb, Kb, Vt, mask, Og);
}

__global__ __launch_bounds__(512) void outproj_k(
    const bf16_t* Og, const float* Wout, const float* bout, float* out)
{
    __shared__ __align__(16) unsigned char smem[55296];
    outproj_body(smem, blockIdx.x, Og, Wout, bout, out);
}

extern "C" void kernel_launch(void* const* d_in, const int* in_sizes, int n_in,
                              void* d_out, int out_size, void* d_ws, size_t ws_size,
                              hipStream_t stream)
{
    const float* values  = (const float*)d_in[0];
    const float* keys    = (const float*)d_in[1];
    const float* queries = (const float*)d_in[2];
    const int*   mask    = (const int*)d_in[3];
    const float* Wq      = (const float*)d_in[4];
    const float* Wk      = (const float*)d_in[5];
    const float* Wv      = (const float*)d_in[6];
    const float* Wout    = (const float*)d_in[7];
    const float* bout    = (const float*)d_in[8];
    float* out = (float*)d_out;

    const size_t M8 = 8ull * 1024 * 1024;
    bf16_t* Qb = (bf16_t*)d_ws;
    bf16_t* Kb = (bf16_t*)((char*)d_ws + 1 * M8);
    bf16_t* Vt = (bf16_t*)((char*)d_ws + 2 * M8);
    bf16_t* Og = (bf16_t*)((char*)d_ws + 3 * M8);

    void* args[] = {
        (void*)&values, (void*)&keys, (void*)&queries, (void*)&mask,
        (void*)&Wq, (void*)&Wk, (void*)&Wv, (void*)&Wout, (void*)&bout,
        (void*)&out, (void*)&Qb, (void*)&Kb, (void*)&Vt, (void*)&Og,
    };
    hipError_t err = hipLaunchCooperativeKernel(
        (const void*)fused_kernel, dim3(512), dim3(512), args, 0, stream);
    if (err != hipSuccess) {
        (void)hipGetLastError();   // clear; fall back to 3 plain launches
        proj_k<<<dim3(512), 512, 0, stream>>>(
            queries, keys, values, Wq, Wk, Wv, Qb, Kb, Vt);
        attn_k<<<dim3(512), 512, 0, stream>>>(Qb, Kb, Vt, mask, Og);
        outproj_k<<<dim3(512), 512, 0, stream>>>(Og, Wout, bout, out);
    }
}

// Round 8
// 192.212 us; speedup vs baseline: 1.6678x; 1.6678x over previous
//
#include <hip/hip_runtime.h>
#include <hip/hip_bf16.h>

// SelfAttention: B=2, S=2048, H=16, D=64, E=1024
// proj (QKV linears; Q pre-scaled by 1/sqrt(E); Q/K d-channels sigma-permuted
//   identically -> wide coalesced stores; V stored key-permuted) ->
// flash attn (S^T form, K=32 PV via key-permutation, no-max softmax,
//   mask as additive bias in the S accumulator, lsum via ones-MFMA;
//   q-tile 64, 256 thr = 4 waves: wq=w&1 -> 32 q-rows, wk=w>>1 -> 32-key half;
//   grid 1024 blocks = 4 blocks/CU (fixes the 2-blocks/CU grid cap of R5);
//   partner waves (w, w^2) combine partial O/lsum via LDS) ->
// out GEMM + bias (128x64 tiles, Wout fp32->bf16 inline).
// ws: Qb[0,8M) Kb[8M,16M) Vt[16M,24M) Og[24M,32M).
//
// sigma (Q/K channel permutation, contraction-internal so QK^T invariant):
//   logical channel ct*16+q4*4+i  ->  physical q4*16+ct*4+i.
// kappa (key permutation within each 32-block, shared by P-frags and Vt):
//   logical k = hi*16+q4*4+i  ->  physical q4*8+hi*4+i.

#define NHB 16
#define HS  64
#define EMB 1024
#define BB  2
#define SS  2048
#define NT  (SS / 64)

typedef __bf16 bf16_t;
typedef bf16_t bf16x8 __attribute__((ext_vector_type(8)));
typedef bf16_t bf16x4 __attribute__((ext_vector_type(4)));
typedef float  f32x4  __attribute__((ext_vector_type(4)));

__device__ __forceinline__ f32x4 mfma16(bf16x8 a, bf16x8 b, f32x4 c) {
    return __builtin_amdgcn_mfma_f32_16x16x32_bf16(a, b, c, 0, 0, 0);
}

// ---------------------------------------------------------------------------
// Kernel 1: Q/K/V projections. grid (S/128, H, B), 512 threads = 8 waves.
// Wave w computes s-rows [w*16, w*16+16); X for phase p+1 prefetched in regs.
// ---------------------------------------------------------------------------
__global__ __launch_bounds__(512) void proj_kernel(
    const float* __restrict__ queries, const float* __restrict__ keys,
    const float* __restrict__ values,
    const float* __restrict__ Wq, const float* __restrict__ Wk,
    const float* __restrict__ Wv,
    bf16_t* __restrict__ Qb, bf16_t* __restrict__ Kb, bf16_t* __restrict__ Vt)
{
    __shared__ bf16_t Ws[3][64][72];
    __shared__ bf16_t Xs[128][72];

    const int tid  = threadIdx.x;
    const int wave = tid >> 6, lane = tid & 63;
    const int q4 = lane >> 4, l16 = lane & 15;
    const int s0 = blockIdx.x * 128;
    const int h  = blockIdx.y, n = blockIdx.z;

    #pragma unroll
    for (int i = 0; i < 6; ++i) {
        int g = i * 512 + tid;
        int mW = g >> 10;                 // uniform per i
        int idx4 = g & 1023;
        const float* wp = (mW == 0) ? Wq : (mW == 1) ? Wk : Wv;
        float4 v = ((const float4*)wp)[idx4];
        int r = idx4 >> 4, c = (idx4 & 15) * 4;
        Ws[mW][r][c+0] = (bf16_t)v.x; Ws[mW][r][c+1] = (bf16_t)v.y;
        Ws[mW][r][c+2] = (bf16_t)v.z; Ws[mW][r][c+3] = (bf16_t)v.w;
    }

    const size_t headBase = (size_t)(n * NHB + h) * SS * HS;

    float4 gx[4];
    auto loadX = [&](const float* xp) {
        #pragma unroll
        for (int i = 0; i < 4; ++i) {
            int idx4 = i * 512 + tid;                 // 2048 chunks: 128 x 16
            int r = idx4 >> 4, c = (idx4 & 15) * 4;
            gx[i] = *(const float4*)&xp[((size_t)(n * SS + s0 + r)) * EMB + h * HS + c];
        }
    };
    loadX(queries);

    for (int p = 0; p < 3; ++p) {
        __syncthreads();
        #pragma unroll
        for (int i = 0; i < 4; ++i) {
            int idx4 = i * 512 + tid;
            int r = idx4 >> 4, c = (idx4 & 15) * 4;
            Xs[r][c+0] = (bf16_t)gx[i].x; Xs[r][c+1] = (bf16_t)gx[i].y;
            Xs[r][c+2] = (bf16_t)gx[i].z; Xs[r][c+3] = (bf16_t)gx[i].w;
        }
        if (p == 0) loadX(keys);
        else if (p == 1) loadX(values);
        __syncthreads();

        bf16x8 xf[2], wf[4][2];
        #pragma unroll
        for (int kk = 0; kk < 2; ++kk)
            xf[kk] = *(const bf16x8*)&Xs[wave * 16 + l16][kk * 32 + q4 * 8];
        #pragma unroll
        for (int ct = 0; ct < 4; ++ct)
            #pragma unroll
            for (int kk = 0; kk < 2; ++kk)
                wf[ct][kk] = *(const bf16x8*)&Ws[p][ct * 16 + l16][kk * 32 + q4 * 8];

        if (p < 2) {
            // sigma gather: phys channel = q4*16 + ct*4 + i -> two 16B stores
            bf16_t* dst = (p == 0) ? Qb : Kb;
            const float sc = (p == 0) ? 0.03125f : 1.0f;
            bf16x8 lo, hi;
            #pragma unroll
            for (int ct = 0; ct < 4; ++ct) {
                f32x4 acc = {};
                acc = mfma16(wf[ct][0], xf[0], acc);
                acc = mfma16(wf[ct][1], xf[1], acc);
                #pragma unroll
                for (int i = 0; i < 4; ++i) {
                    bf16_t v = (bf16_t)(acc[i] * sc);
                    if (ct < 2) lo[ct * 4 + i] = v;
                    else        hi[(ct - 2) * 4 + i] = v;
                }
            }
            bf16_t* rp = dst + headBase
                + (size_t)(s0 + wave * 16 + l16) * HS + q4 * 16;
            *(bf16x8*)rp = lo;
            *(bf16x8*)(rp + 8) = hi;
        } else {
            #pragma unroll
            for (int ct = 0; ct < 4; ++ct) {
                f32x4 acc = {};
                acc = mfma16(xf[0], wf[ct][0], acc);
                acc = mfma16(xf[1], wf[ct][1], acc);
                bf16x4 pk;
                #pragma unroll
                for (int i = 0; i < 4; ++i) pk[i] = (bf16_t)acc[i];
                *(bf16x4*)&Vt[headBase + (size_t)(ct * 16 + l16) * SS
                              + s0 + (wave >> 1) * 32 + q4 * 8 + (wave & 1) * 4] = pk;
            }
        }
    }
}

// ---------------------------------------------------------------------------
// Kernel 2: flash attention. grid (S/64, H, B) = 1024 blocks, 256 threads.
// wq = w&1 -> 32 q-rows; wk = w>>1 -> 32-key half of each 64-key tile.
// ---------------------------------------------------------------------------
__global__ __launch_bounds__(256) void attn_kernel(
    const bf16_t* __restrict__ Qb, const bf16_t* __restrict__ Kb,
    const bf16_t* __restrict__ Vt, const int* __restrict__ mask,
    bf16_t* __restrict__ Og)
{
    __shared__ __align__(16) unsigned char smem[37376];
    auto Ks = (bf16_t(*)[64][72])(smem);            // [2][key][d]
    auto Vs = (bf16_t(*)[64][72])(smem + 18432);    // [2][d][kappa-key]
    auto Ms = (float(*)[64])(smem + 36864);         // [2][64] additive bias
    float* fbuf = (float*)smem;                      // combine: 16 KB
    float* lbuf = (float*)(smem + 16384);            // combine: 1 KB

    const int tid = threadIdx.x;
    const int w = tid >> 6, lane = tid & 63;
    const int q4 = lane >> 4, l16 = lane & 15;
    const int wq = w & 1, wk = w >> 1;
    const int qt = blockIdx.x, h = blockIdx.y, n = blockIdx.z;
    const size_t headBase = (size_t)(n * NHB + h) * SS * HS;
    const int* mrow = mask + n * SS;

    // staging: 256 threads x 2 chunks each for K and V (64x64 tiles)
    const int sr0 = tid >> 3, sc0 = (tid & 7) * 8;   // rows 0..31
    const int sr1 = sr0 + 32;                         // rows 32..63
    const bf16_t* kb0 = Kb + headBase + (size_t)sr0 * HS + sc0;
    const bf16_t* kb1 = Kb + headBase + (size_t)sr1 * HS + sc0;
    const bf16_t* vt0 = Vt + headBase + (size_t)sr0 * SS + sc0;
    const bf16_t* vt1 = Vt + headBase + (size_t)sr1 * SS + sc0;

    bf16x8 bq[2][2];
    #pragma unroll
    for (int st = 0; st < 2; ++st) {
        const bf16_t* qptr = Qb + headBase
            + (size_t)(qt * 64 + wq * 32 + st * 16 + l16) * HS;
        bq[st][0] = *(const bf16x8*)&qptr[q4 * 8];
        bq[st][1] = *(const bf16x8*)&qptr[32 + q4 * 8];
    }

    bf16x8 ones;
    #pragma unroll
    for (int i = 0; i < 8; ++i) ones[i] = (bf16_t)1.0f;

    f32x4 oaccT[2][4] = {};
    f32x4 lacc[2] = {};

    // prologue: stage tile 0
    *(bf16x8*)&Ks[0][sr0][sc0] = *(const bf16x8*)kb0;
    *(bf16x8*)&Ks[0][sr1][sc0] = *(const bf16x8*)kb1;
    *(bf16x8*)&Vs[0][sr0][sc0] = *(const bf16x8*)vt0;
    *(bf16x8*)&Vs[0][sr1][sc0] = *(const bf16x8*)vt1;
    if (tid < 64) Ms[0][tid] = mrow[tid] ? 0.0f : -3e38f;
    __syncthreads();

    for (int kt = 0; kt < NT; ++kt) {
        const int cur = kt & 1;
        const bool has_next = (kt + 1) < NT;
        bf16x8 gk0, gk1, gv0, gv1; float gm = 0.f;
        if (has_next) {
            const int k0n = (kt + 1) * 64;
            gk0 = *(const bf16x8*)(kb0 + (size_t)k0n * HS);
            gk1 = *(const bf16x8*)(kb1 + (size_t)k0n * HS);
            gv0 = *(const bf16x8*)(vt0 + k0n);
            gv1 = *(const bf16x8*)(vt1 + k0n);
            if (tid < 64) gm = mrow[k0n + tid] ? 0.0f : -3e38f;
        }

        // S^T = bias + K.Q^T over this wave's 32-key half
        f32x4 sacc[2][2];
        #pragma unroll
        for (int c2 = 0; c2 < 2; ++c2) {
            const int ct = wk * 2 + c2;
            float4 bias = *(const float4*)&Ms[cur][ct * 16 + q4 * 4];
            f32x4 b4 = {bias.x, bias.y, bias.z, bias.w};
            sacc[0][c2] = b4; sacc[1][c2] = b4;
            bf16x8 ak0 = *(const bf16x8*)&Ks[cur][ct * 16 + l16][q4 * 8];
            bf16x8 ak1 = *(const bf16x8*)&Ks[cur][ct * 16 + l16][32 + q4 * 8];
            #pragma unroll
            for (int st = 0; st < 2; ++st) {
                sacc[st][c2] = mfma16(ak0, bq[st][0], sacc[st][c2]);
                sacc[st][c2] = mfma16(ak1, bq[st][1], sacc[st][c2]);
            }
        }

        // P = exp(S): single fast-exp, no mask mul, no scalar lsum
        bf16x4 pv[2][2];
        #pragma unroll
        for (int c2 = 0; c2 < 2; ++c2)
            #pragma unroll
            for (int st = 0; st < 2; ++st) {
                bf16x4 pk;
                #pragma unroll
                for (int j = 0; j < 4; ++j)
                    pk[j] = (bf16_t)__expf(sacc[st][c2][j]);
                pv[st][c2] = pk;
            }

        // O^T += V^T.P^T ; lsum += ones.P^T
        bf16x8 pa[2];
        #pragma unroll
        for (int st = 0; st < 2; ++st)
            pa[st] = __builtin_shufflevector(pv[st][0], pv[st][1],
                                             0, 1, 2, 3, 4, 5, 6, 7);
        #pragma unroll
        for (int dt = 0; dt < 4; ++dt) {
            bf16x8 av = *(const bf16x8*)&Vs[cur][dt * 16 + l16][wk * 32 + q4 * 8];
            oaccT[0][dt] = mfma16(av, pa[0], oaccT[0][dt]);
            oaccT[1][dt] = mfma16(av, pa[1], oaccT[1][dt]);
        }
        lacc[0] = mfma16(ones, pa[0], lacc[0]);
        lacc[1] = mfma16(ones, pa[1], lacc[1]);

        if (has_next) {
            const int nxt = 1 - cur;
            *(bf16x8*)&Ks[nxt][sr0][sc0] = gk0;
            *(bf16x8*)&Ks[nxt][sr1][sc0] = gk1;
            *(bf16x8*)&Vs[nxt][sr0][sc0] = gv0;
            *(bf16x8*)&Vs[nxt][sr1][sc0] = gv1;
            if (tid < 64) Ms[nxt][tid] = gm;
        }
        __syncthreads();
    }

    float ls[2] = {lacc[0][0], lacc[1][0]};

    // combine partner halves: waves 2,3 publish, waves 0,1 reduce + store
    if (w >= 2) {
        const int lanecol = wq * 64 + lane;
        #pragma unroll
        for (int st = 0; st < 2; ++st) {
            #pragma unroll
            for (int dt = 0; dt < 4; ++dt)
                #pragma unroll
                for (int j = 0; j < 4; ++j)
                    fbuf[(st * 16 + dt * 4 + j) * 128 + lanecol] = oaccT[st][dt][j];
            lbuf[st * 128 + lanecol] = ls[st];
        }
    }
    __syncthreads();
    if (w < 2) {
        const int lanecol = wq * 64 + lane;
        #pragma unroll
        for (int st = 0; st < 2; ++st) {
            #pragma unroll
            for (int dt = 0; dt < 4; ++dt)
                #pragma unroll
                for (int j = 0; j < 4; ++j)
                    oaccT[st][dt][j] += fbuf[(st * 16 + dt * 4 + j) * 128 + lanecol];
            ls[st] += lbuf[st * 128 + lanecol];
        }
        #pragma unroll
        for (int st = 0; st < 2; ++st) {
            const float inv = 1.f / ls[st];
            const int qrow = qt * 64 + wq * 32 + st * 16 + l16;
            bf16_t* obase = Og + ((size_t)(n * SS + qrow)) * EMB + h * HS;
            #pragma unroll
            for (int dt = 0; dt < 4; ++dt) {
                bf16x4 ov;
                #pragma unroll
                for (int j = 0; j < 4; ++j) ov[j] = (bf16_t)(oaccT[st][dt][j] * inv);
                *(bf16x4*)&obase[dt * 16 + q4 * 4] = ov;
            }
        }
    }
}

// ---------------------------------------------------------------------------
// Kernel 3: out = Og @ Wout.T + bout. grid (BS/128, EMB/64), 512 threads.
// 128x64 tile, double-buffered; Wout staged fp32 -> bf16 inline.
// ---------------------------------------------------------------------------
__global__ __launch_bounds__(512) void outproj_kernel(
    const bf16_t* __restrict__ Og, const float* __restrict__ Wout,
    const float* __restrict__ bout, float* __restrict__ out)
{
    __shared__ bf16_t As[2][128][72];
    __shared__ bf16_t Bs[2][64][72];
    const int tid = threadIdx.x;
    const int w = tid >> 6, lane = tid & 63;
    const int q4 = lane >> 4, l16 = lane & 15;
    const int wr = w >> 1, wc = w & 1;
    const int t0 = blockIdx.x * 128, c0 = blockIdx.y * 64;

    const int sr0 = tid >> 3, sc0 = (tid & 7) * 8;
    const int sr1 = sr0 + 64;
    const bf16_t* a0 = Og + (size_t)(t0 + sr0) * EMB + sc0;
    const bf16_t* a1 = Og + (size_t)(t0 + sr1) * EMB + sc0;
    const float*  b0 = Wout + (size_t)(c0 + sr0) * EMB + sc0;

    auto cvt8 = [](float4 x, float4 y) {
        bf16x8 r;
        r[0] = (bf16_t)x.x; r[1] = (bf16_t)x.y; r[2] = (bf16_t)x.z; r[3] = (bf16_t)x.w;
        r[4] = (bf16_t)y.x; r[5] = (bf16_t)y.y; r[6] = (bf16_t)y.z; r[7] = (bf16_t)y.w;
        return r;
    };

    f32x4 acc[2][2] = {};

    *(bf16x8*)&As[0][sr0][sc0] = *(const bf16x8*)a0;
    *(bf16x8*)&As[0][sr1][sc0] = *(const bf16x8*)a1;
    *(bf16x8*)&Bs[0][sr0][sc0] = cvt8(*(const float4*)b0, *(const float4*)(b0 + 4));
    __syncthreads();

    const int NE = EMB / 64;
    for (int et = 0; et < NE; ++et) {
        const int cur = et & 1;
        const bool has_next = (et + 1) < NE;
        bf16x8 ga0, ga1; float4 gb0, gb1;
        if (has_next) {
            const int e0 = (et + 1) * 64;
            ga0 = *(const bf16x8*)(a0 + e0); ga1 = *(const bf16x8*)(a1 + e0);
            gb0 = *(const float4*)(b0 + e0); gb1 = *(const float4*)(b0 + e0 + 4);
        }

        bf16x8 af[2][2], bfr[2][2];
        #pragma unroll
        for (int st = 0; st < 2; ++st)
            #pragma unroll
            for (int kk = 0; kk < 2; ++kk)
                af[st][kk] = *(const bf16x8*)&As[cur][wr * 32 + st * 16 + l16][kk * 32 + q4 * 8];
        #pragma unroll
        for (int ct = 0; ct < 2; ++ct)
            #pragma unroll
            for (int kk = 0; kk < 2; ++kk)
                bfr[ct][kk] = *(const bf16x8*)&Bs[cur][wc * 32 + ct * 16 + l16][kk * 32 + q4 * 8];
        #pragma unroll
        for (int st = 0; st < 2; ++st)
            #pragma unroll
            for (int ct = 0; ct < 2; ++ct) {
                acc[st][ct] = mfma16(af[st][0], bfr[ct][0], acc[st][ct]);
                acc[st][ct] = mfma16(af[st][1], bfr[ct][1], acc[st][ct]);
            }

        if (has_next) {
            const int nxt = 1 - cur;
            *(bf16x8*)&As[nxt][sr0][sc0] = ga0;
            *(bf16x8*)&As[nxt][sr1][sc0] = ga1;
            *(bf16x8*)&Bs[nxt][sr0][sc0] = cvt8(gb0, gb1);
        }
        __syncthreads();
    }

    #pragma unroll
    for (int ct = 0; ct < 2; ++ct) {
        const int c = c0 + wc * 32 + ct * 16 + l16;
        const float bias = bout[c];
        #pragma unroll
        for (int st = 0; st < 2; ++st)
            #pragma unroll
            for (int i = 0; i < 4; ++i)
                out[(size_t)(t0 + wr * 32 + st * 16 + q4 * 4 + i) * EMB + c]
                    = acc[st][ct][i] + bias;
    }
}

extern "C" void kernel_launch(void* const* d_in, const int* in_sizes, int n_in,
                              void* d_out, int out_size, void* d_ws, size_t ws_size,
                              hipStream_t stream)
{
    const float* values  = (const float*)d_in[0];
    const float* keys    = (const float*)d_in[1];
    const float* queries = (const float*)d_in[2];
    const int*   mask    = (const int*)d_in[3];
    const float* Wq      = (const float*)d_in[4];
    const float* Wk      = (const float*)d_in[5];
    const float* Wv      = (const float*)d_in[6];
    const float* Wout    = (const float*)d_in[7];
    const float* bout    = (const float*)d_in[8];
    float* out = (float*)d_out;

    const size_t M8 = 8ull * 1024 * 1024;
    bf16_t* Qb = (bf16_t*)d_ws;
    bf16_t* Kb = (bf16_t*)((char*)d_ws + 1 * M8);
    bf16_t* Vt = (bf16_t*)((char*)d_ws + 2 * M8);
    bf16_t* Og = (bf16_t*)((char*)d_ws + 3 * M8);

    proj_kernel<<<dim3(SS / 128, NHB, BB), 512, 0, stream>>>(
        queries, keys, values, Wq, Wk, Wv, Qb, Kb, Vt);
    attn_kernel<<<dim3(SS / 64, NHB, BB), 256, 0, stream>>>(
        Qb, Kb, Vt, mask, Og);
    outproj_kernel<<<dim3((BB * SS) / 128, EMB / 64), 512, 0, stream>>>(
        Og, Wout, bout, out);
}

// Round 9
// 171.030 us; speedup vs baseline: 1.8744x; 1.1239x over previous
//
#include <hip/hip_runtime.h>
#include <hip/hip_bf16.h>

// SelfAttention: B=2, S=2048, H=16, D=64, E=1024
// == Round-5 structure (measured best: attn 47.5us, total 171.2us) with ONE
// change: Q carries log2e/sqrt(E) so P = v_exp_f32(S) directly (raw exp2
// builtin), removing 16 v_mul per wave per k-tile vs __expf.
//
// proj (QKV linears; Q pre-scaled by log2e/32; Q/K d-channels sigma-permuted
//   identically -> wide coalesced stores; V stored key-permuted) ->
// flash attn (S^T form, K=32 PV via key-permutation, no-max softmax,
//   mask as additive bias in the S accumulator, lsum via ones-MFMA,
//   waves 0-3 keys 0-31 / waves 4-7 keys 32-63, LDS combine at end) ->
// out GEMM + bias (128x64 tiles, Wout fp32->bf16 inline).
// ws: Qb[0,8M) Kb[8M,16M) Vt[16M,24M) Og[24M,32M).
//
// sigma (Q/K channel permutation, contraction-internal so QK^T invariant):
//   logical channel ct*16+q4*4+i  ->  physical q4*16+ct*4+i.
// kappa (key permutation within each 32-block, shared by P-frags and Vt):
//   logical k = hi*16+q4*4+i  ->  physical q4*8+hi*4+i.

#define NHB 16
#define HS  64
#define EMB 1024
#define BB  2
#define SS  2048
#define NT  (SS / 64)

typedef __bf16 bf16_t;
typedef bf16_t bf16x8 __attribute__((ext_vector_type(8)));
typedef bf16_t bf16x4 __attribute__((ext_vector_type(4)));
typedef float  f32x4  __attribute__((ext_vector_type(4)));

__device__ __forceinline__ f32x4 mfma16(bf16x8 a, bf16x8 b, f32x4 c) {
    return __builtin_amdgcn_mfma_f32_16x16x32_bf16(a, b, c, 0, 0, 0);
}

// raw v_exp_f32 (computes 2^x) -- NOT libm exp2f (slow guarded sequence)
__device__ __forceinline__ float fast_exp2(float x) {
#if __has_builtin(__builtin_amdgcn_exp2f)
    return __builtin_amdgcn_exp2f(x);
#else
    float r;
    asm("v_exp_f32 %0, %1" : "=v"(r) : "v"(x));
    return r;
#endif
}

// ---------------------------------------------------------------------------
// Kernel 1: Q/K/V projections. grid (S/128, H, B), 512 threads = 8 waves.
// Wave w computes s-rows [w*16, w*16+16); X for phase p+1 prefetched in regs.
// ---------------------------------------------------------------------------
__global__ __launch_bounds__(512) void proj_kernel(
    const float* __restrict__ queries, const float* __restrict__ keys,
    const float* __restrict__ values,
    const float* __restrict__ Wq, const float* __restrict__ Wk,
    const float* __restrict__ Wv,
    bf16_t* __restrict__ Qb, bf16_t* __restrict__ Kb, bf16_t* __restrict__ Vt)
{
    __shared__ bf16_t Ws[3][64][72];
    __shared__ bf16_t Xs[128][72];

    const int tid  = threadIdx.x;
    const int wave = tid >> 6, lane = tid & 63;
    const int q4 = lane >> 4, l16 = lane & 15;
    const int s0 = blockIdx.x * 128;
    const int h  = blockIdx.y, n = blockIdx.z;

    #pragma unroll
    for (int i = 0; i < 6; ++i) {
        int g = i * 512 + tid;
        int mW = g >> 10;                 // uniform per i
        int idx4 = g & 1023;
        const float* wp = (mW == 0) ? Wq : (mW == 1) ? Wk : Wv;
        float4 v = ((const float4*)wp)[idx4];
        int r = idx4 >> 4, c = (idx4 & 15) * 4;
        Ws[mW][r][c+0] = (bf16_t)v.x; Ws[mW][r][c+1] = (bf16_t)v.y;
        Ws[mW][r][c+2] = (bf16_t)v.z; Ws[mW][r][c+3] = (bf16_t)v.w;
    }

    const size_t headBase = (size_t)(n * NHB + h) * SS * HS;

    float4 gx[4];
    auto loadX = [&](const float* xp) {
        #pragma unroll
        for (int i = 0; i < 4; ++i) {
            int idx4 = i * 512 + tid;                 // 2048 chunks: 128 x 16
            int r = idx4 >> 4, c = (idx4 & 15) * 4;
            gx[i] = *(const float4*)&xp[((size_t)(n * SS + s0 + r)) * EMB + h * HS + c];
        }
    };
    loadX(queries);

    for (int p = 0; p < 3; ++p) {
        __syncthreads();
        #pragma unroll
        for (int i = 0; i < 4; ++i) {
            int idx4 = i * 512 + tid;
            int r = idx4 >> 4, c = (idx4 & 15) * 4;
            Xs[r][c+0] = (bf16_t)gx[i].x; Xs[r][c+1] = (bf16_t)gx[i].y;
            Xs[r][c+2] = (bf16_t)gx[i].z; Xs[r][c+3] = (bf16_t)gx[i].w;
        }
        if (p == 0) loadX(keys);
        else if (p == 1) loadX(values);
        __syncthreads();

        bf16x8 xf[2], wf[4][2];
        #pragma unroll
        for (int kk = 0; kk < 2; ++kk)
            xf[kk] = *(const bf16x8*)&Xs[wave * 16 + l16][kk * 32 + q4 * 8];
        #pragma unroll
        for (int ct = 0; ct < 4; ++ct)
            #pragma unroll
            for (int kk = 0; kk < 2; ++kk)
                wf[ct][kk] = *(const bf16x8*)&Ws[p][ct * 16 + l16][kk * 32 + q4 * 8];

        if (p < 2) {
            // sigma gather: phys channel = q4*16 + ct*4 + i -> two 16B stores
            bf16_t* dst = (p == 0) ? Qb : Kb;
            // Q carries log2e/sqrt(EMB) so attn can use raw v_exp_f32 (2^x)
            const float sc = (p == 0) ? (0.03125f * 1.44269504f) : 1.0f;
            bf16x8 lo, hi;
            #pragma unroll
            for (int ct = 0; ct < 4; ++ct) {
                f32x4 acc = {};
                acc = mfma16(wf[ct][0], xf[0], acc);
                acc = mfma16(wf[ct][1], xf[1], acc);
                #pragma unroll
                for (int i = 0; i < 4; ++i) {
                    bf16_t v = (bf16_t)(acc[i] * sc);
                    if (ct < 2) lo[ct * 4 + i] = v;
                    else        hi[(ct - 2) * 4 + i] = v;
                }
            }
            bf16_t* rp = dst + headBase
                + (size_t)(s0 + wave * 16 + l16) * HS + q4 * 16;
            *(bf16x8*)rp = lo;
            *(bf16x8*)(rp + 8) = hi;
        } else {
            #pragma unroll
            for (int ct = 0; ct < 4; ++ct) {
                f32x4 acc = {};
                acc = mfma16(xf[0], wf[ct][0], acc);
                acc = mfma16(xf[1], wf[ct][1], acc);
                bf16x4 pk;
                #pragma unroll
                for (int i = 0; i < 4; ++i) pk[i] = (bf16_t)acc[i];
                *(bf16x4*)&Vt[headBase + (size_t)(ct * 16 + l16) * SS
                              + s0 + (wave >> 1) * 32 + q4 * 8 + (wave & 1) * 4] = pk;
            }
        }
    }
}

// ---------------------------------------------------------------------------
// Kernel 2: flash attention. grid (S/128, H, B), 512 threads = 8 waves.
// wq = w&3 selects 32 q-rows; wk = w>>2 selects the 32-key half of each tile.
// Mask enters as additive bias preloaded into the S accumulator; lsum is
// computed by an extra MFMA against a ones A-operand (replicated per lane).
// ---------------------------------------------------------------------------
__global__ __launch_bounds__(512) void attn_kernel(
    const bf16_t* __restrict__ Qb, const bf16_t* __restrict__ Kb,
    const bf16_t* __restrict__ Vt, const int* __restrict__ mask,
    bf16_t* __restrict__ Og)
{
    __shared__ __align__(16) unsigned char smem[37376];
    auto Ks = (bf16_t(*)[64][72])(smem);            // [2][key][d]
    auto Vs = (bf16_t(*)[64][72])(smem + 18432);    // [2][d][kappa-key]
    auto Ms = (float(*)[64])(smem + 36864);         // [2][64] additive bias
    float* fbuf = (float*)smem;                      // combine: 32 KB
    float* lbuf = (float*)(smem + 32768);            // combine: 2 KB

    const int tid = threadIdx.x;
    const int w = tid >> 6, lane = tid & 63;
    const int q4 = lane >> 4, l16 = lane & 15;
    const int wq = w & 3, wk = w >> 2;
    const int qt = blockIdx.x, h = blockIdx.y, n = blockIdx.z;
    const size_t headBase = (size_t)(n * NHB + h) * SS * HS;
    const int* mrow = mask + n * SS;

    const int sr = tid >> 3, sc = (tid & 7) * 8;
    const bf16_t* kb_src = Kb + headBase + (size_t)sr * HS + sc;
    const bf16_t* vt_src = Vt + headBase + (size_t)sr * SS + sc;

    bf16x8 bq[2][2];
    #pragma unroll
    for (int st = 0; st < 2; ++st) {
        const bf16_t* qptr = Qb + headBase
            + (size_t)(qt * 128 + wq * 32 + st * 16 + l16) * HS;
        bq[st][0] = *(const bf16x8*)&qptr[q4 * 8];
        bq[st][1] = *(const bf16x8*)&qptr[32 + q4 * 8];
    }

    bf16x8 ones;
    #pragma unroll
    for (int i = 0; i < 8; ++i) ones[i] = (bf16_t)1.0f;

    f32x4 oaccT[2][4] = {};
    f32x4 lacc[2] = {};

    *(bf16x8*)&Ks[0][sr][sc] = *(const bf16x8*)kb_src;
    *(bf16x8*)&Vs[0][sr][sc] = *(const bf16x8*)vt_src;
    if (tid < 64) Ms[0][tid] = mrow[tid] ? 0.0f : -3e38f;
    __syncthreads();

    for (int kt = 0; kt < NT; ++kt) {
        const int cur = kt & 1;
        const bool has_next = (kt + 1) < NT;
        bf16x8 gk, gv; float gm = 0.f;
        if (has_next) {
            const int k0n = (kt + 1) * 64;
            gk = *(const bf16x8*)(kb_src + (size_t)k0n * HS);
            gv = *(const bf16x8*)(vt_src + k0n);
            if (tid < 64) gm = mrow[k0n + tid] ? 0.0f : -3e38f;
        }

        // S^T = bias + K.Q^T over this wave's 32-key half
        f32x4 sacc[2][2];
        #pragma unroll
        for (int c2 = 0; c2 < 2; ++c2) {
            const int ct = wk * 2 + c2;
            float4 bias = *(const float4*)&Ms[cur][ct * 16 + q4 * 4];
            f32x4 b4 = {bias.x, bias.y, bias.z, bias.w};
            sacc[0][c2] = b4; sacc[1][c2] = b4;
            bf16x8 ak0 = *(const bf16x8*)&Ks[cur][ct * 16 + l16][q4 * 8];
            bf16x8 ak1 = *(const bf16x8*)&Ks[cur][ct * 16 + l16][32 + q4 * 8];
            #pragma unroll
            for (int st = 0; st < 2; ++st) {
                sacc[st][c2] = mfma16(ak0, bq[st][0], sacc[st][c2]);
                sacc[st][c2] = mfma16(ak1, bq[st][1], sacc[st][c2]);
            }
        }

        // P = 2^S (Q carries log2e/32): one v_exp_f32 per element, no mul
        bf16x4 pv[2][2];
        #pragma unroll
        for (int c2 = 0; c2 < 2; ++c2)
            #pragma unroll
            for (int st = 0; st < 2; ++st) {
                bf16x4 pk;
                #pragma unroll
                for (int j = 0; j < 4; ++j)
                    pk[j] = (bf16_t)fast_exp2(sacc[st][c2][j]);
                pv[st][c2] = pk;
            }

        // O^T += V^T.P^T ; lsum += ones.P^T
        bf16x8 pa[2];
        #pragma unroll
        for (int st = 0; st < 2; ++st)
            pa[st] = __builtin_shufflevector(pv[st][0], pv[st][1],
                                             0, 1, 2, 3, 4, 5, 6, 7);
        #pragma unroll
        for (int dt = 0; dt < 4; ++dt) {
            bf16x8 av = *(const bf16x8*)&Vs[cur][dt * 16 + l16][wk * 32 + q4 * 8];
            oaccT[0][dt] = mfma16(av, pa[0], oaccT[0][dt]);
            oaccT[1][dt] = mfma16(av, pa[1], oaccT[1][dt]);
        }
        lacc[0] = mfma16(ones, pa[0], lacc[0]);
        lacc[1] = mfma16(ones, pa[1], lacc[1]);

        if (has_next) {
            const int nxt = 1 - cur;
            *(bf16x8*)&Ks[nxt][sr][sc] = gk;
            *(bf16x8*)&Vs[nxt][sr][sc] = gv;
            if (tid < 64) Ms[nxt][tid] = gm;
        }
        __syncthreads();
    }

    float ls[2] = {lacc[0][0], lacc[1][0]};

    // combine partner halves: waves 4-7 publish, waves 0-3 reduce + store
    if (w >= 4) {
        const int lanecol = wq * 64 + lane;
        #pragma unroll
        for (int st = 0; st < 2; ++st) {
            #pragma unroll
            for (int dt = 0; dt < 4; ++dt)
                #pragma unroll
                for (int j = 0; j < 4; ++j)
                    fbuf[(st * 16 + dt * 4 + j) * 256 + lanecol] = oaccT[st][dt][j];
            lbuf[st * 256 + lanecol] = ls[st];
        }
    }
    __syncthreads();
    if (w < 4) {
        const int lanecol = wq * 64 + lane;
        #pragma unroll
        for (int st = 0; st < 2; ++st) {
            #pragma unroll
            for (int dt = 0; dt < 4; ++dt)
                #pragma unroll
                for (int j = 0; j < 4; ++j)
                    oaccT[st][dt][j] += fbuf[(st * 16 + dt * 4 + j) * 256 + lanecol];
            ls[st] += lbuf[st * 256 + lanecol];
        }
        #pragma unroll
        for (int st = 0; st < 2; ++st) {
            const float inv = 1.f / ls[st];
            const int qrow = qt * 128 + wq * 32 + st * 16 + l16;
            bf16_t* obase = Og + ((size_t)(n * SS + qrow)) * EMB + h * HS;
            #pragma unroll
            for (int dt = 0; dt < 4; ++dt) {
                bf16x4 ov;
                #pragma unroll
                for (int j = 0; j < 4; ++j) ov[j] = (bf16_t)(oaccT[st][dt][j] * inv);
                *(bf16x4*)&obase[dt * 16 + q4 * 4] = ov;
            }
        }
    }
}

// ---------------------------------------------------------------------------
// Kernel 3: out = Og @ Wout.T + bout. grid (BS/128, EMB/64), 512 threads.
// 128x64 tile, double-buffered; Wout staged fp32 -> bf16 inline.
// ---------------------------------------------------------------------------
__global__ __launch_bounds__(512) void outproj_kernel(
    const bf16_t* __restrict__ Og, const float* __restrict__ Wout,
    const float* __restrict__ bout, float* __restrict__ out)
{
    __shared__ bf16_t As[2][128][72];
    __shared__ bf16_t Bs[2][64][72];
    const int tid = threadIdx.x;
    const int w = tid >> 6, lane = tid & 63;
    const int q4 = lane >> 4, l16 = lane & 15;
    const int wr = w >> 1, wc = w & 1;
    const int t0 = blockIdx.x * 128, c0 = blockIdx.y * 64;

    const int sr0 = tid >> 3, sc0 = (tid & 7) * 8;
    const int sr1 = sr0 + 64;
    const bf16_t* a0 = Og + (size_t)(t0 + sr0) * EMB + sc0;
    const bf16_t* a1 = Og + (size_t)(t0 + sr1) * EMB + sc0;
    const float*  b0 = Wout + (size_t)(c0 + sr0) * EMB + sc0;

    auto cvt8 = [](float4 x, float4 y) {
        bf16x8 r;
        r[0] = (bf16_t)x.x; r[1] = (bf16_t)x.y; r[2] = (bf16_t)x.z; r[3] = (bf16_t)x.w;
        r[4] = (bf16_t)y.x; r[5] = (bf16_t)y.y; r[6] = (bf16_t)y.z; r[7] = (bf16_t)y.w;
        return r;
    };

    f32x4 acc[2][2] = {};

    *(bf16x8*)&As[0][sr0][sc0] = *(const bf16x8*)a0;
    *(bf16x8*)&As[0][sr1][sc0] = *(const bf16x8*)a1;
    *(bf16x8*)&Bs[0][sr0][sc0] = cvt8(*(const float4*)b0, *(const float4*)(b0 + 4));
    __syncthreads();

    const int NE = EMB / 64;
    for (int et = 0; et < NE; ++et) {
        const int cur = et & 1;
        const bool has_next = (et + 1) < NE;
        bf16x8 ga0, ga1; float4 gb0, gb1;
        if (has_next) {
            const int e0 = (et + 1) * 64;
            ga0 = *(const bf16x8*)(a0 + e0); ga1 = *(const bf16x8*)(a1 + e0);
            gb0 = *(const float4*)(b0 + e0); gb1 = *(const float4*)(b0 + e0 + 4);
        }

        bf16x8 af[2][2], bfr[2][2];
        #pragma unroll
        for (int st = 0; st < 2; ++st)
            #pragma unroll
            for (int kk = 0; kk < 2; ++kk)
                af[st][kk] = *(const bf16x8*)&As[cur][wr * 32 + st * 16 + l16][kk * 32 + q4 * 8];
        #pragma unroll
        for (int ct = 0; ct < 2; ++ct)
            #pragma unroll
            for (int kk = 0; kk < 2; ++kk)
                bfr[ct][kk] = *(const bf16x8*)&Bs[cur][wc * 32 + ct * 16 + l16][kk * 32 + q4 * 8];
        #pragma unroll
        for (int st = 0; st < 2; ++st)
            #pragma unroll
            for (int ct = 0; ct < 2; ++ct) {
                acc[st][ct] = mfma16(af[st][0], bfr[ct][0], acc[st][ct]);
                acc[st][ct] = mfma16(af[st][1], bfr[ct][1], acc[st][ct]);
            }

        if (has_next) {
            const int nxt = 1 - cur;
            *(bf16x8*)&As[nxt][sr0][sc0] = ga0;
            *(bf16x8*)&As[nxt][sr1][sc0] = ga1;
            *(bf16x8*)&Bs[nxt][sr0][sc0] = cvt8(gb0, gb1);
        }
        __syncthreads();
    }

    #pragma unroll
    for (int ct = 0; ct < 2; ++ct) {
        const int c = c0 + wc * 32 + ct * 16 + l16;
        const float bias = bout[c];
        #pragma unroll
        for (int st = 0; st < 2; ++st)
            #pragma unroll
            for (int i = 0; i < 4; ++i)
                out[(size_t)(t0 + wr * 32 + st * 16 + q4 * 4 + i) * EMB + c]
                    = acc[st][ct][i] + bias;
    }
}

extern "C" void kernel_launch(void* const* d_in, const int* in_sizes, int n_in,
                              void* d_out, int out_size, void* d_ws, size_t ws_size,
                              hipStream_t stream)
{
    const float* values  = (const float*)d_in[0];
    const float* keys    = (const float*)d_in[1];
    const float* queries = (const float*)d_in[2];
    const int*   mask    = (const int*)d_in[3];
    const float* Wq      = (const float*)d_in[4];
    const float* Wk      = (const float*)d_in[5];
    const float* Wv      = (const float*)d_in[6];
    const float* Wout    = (const float*)d_in[7];
    const float* bout    = (const float*)d_in[8];
    float* out = (float*)d_out;

    const size_t M8 = 8ull * 1024 * 1024;
    bf16_t* Qb = (bf16_t*)d_ws;
    bf16_t* Kb = (bf16_t*)((char*)d_ws + 1 * M8);
    bf16_t* Vt = (bf16_t*)((char*)d_ws + 2 * M8);
    bf16_t* Og = (bf16_t*)((char*)d_ws + 3 * M8);

    proj_kernel<<<dim3(SS / 128, NHB, BB), 512, 0, stream>>>(
        queries, keys, values, Wq, Wk, Wv, Qb, Kb, Vt);
    attn_kernel<<<dim3(SS / 128, NHB, BB), 512, 0, stream>>>(
        Qb, Kb, Vt, mask, Og);
    outproj_kernel<<<dim3((BB * SS) / 128, EMB / 64), 512, 0, stream>>>(
        Og, Wout, bout, out);
}